// Round 2
// baseline (279.780 us; speedup 1.0000x reference)
//
#include <hip/hip_runtime.h>
#include <hip/hip_bf16.h>

// STSA fused: k_prep (weights->bf16) -> k_proj_skv (s_k,s_v, bm-major) ->
// k_fused (x->LDS, t_q/t_k/t_v proj, temporal attn, s_q proj, t out-proj,
// spatial attn with register-prefetched gather chunks, s out-proj, single out write).
// All matmuls on mfma_f32_16x16x32_bf16; softmax scale folded into Q
// (0.25*log2e*0.5, the 0.5 compensating hd=16 duplicated into both K-halves),
// exp2, no max-subtract (scores tiny), normalize by 1/l at staging.

typedef __attribute__((ext_vector_type(8))) short bf16x8;
typedef __attribute__((ext_vector_type(4))) short short4v;
typedef __attribute__((ext_vector_type(4))) float f32x4;

#define DEVI static __device__ __forceinline__
#define MFMA(a, b, c) __builtin_amdgcn_mfma_f32_16x16x32_bf16(a, b, c, 0, 0, 0)

static constexpr float QSCALE = 0.25f * 1.44269504088896340736f * 0.5f;

DEVI short f2bfs(float f) {
  __hip_bfloat16 h = __float2bfloat16(f);
  return __builtin_bit_cast(short, h);
}

// 64 rows x 128 bf16 LDS tile, 256B rows, XOR swizzle applied on write AND read.
DEVI int swzb(int row, int colh) {
  return (row * 256 + colh * 2) ^ ((row & 7) << 4);
}

// ---------------------------------------------------------------- k_prep ----
__global__ void __launch_bounds__(256) k_prep(
    const float* __restrict__ twin, const float* __restrict__ tbin,
    const float* __restrict__ twout, const float* __restrict__ tbout,
    const float* __restrict__ swin, const float* __restrict__ sbin,
    const float* __restrict__ swout, const float* __restrict__ sbout,
    short* __restrict__ wcat, float* __restrict__ biasin,
    short* __restrict__ wto, short* __restrict__ wso, float* __restrict__ biasc) {
  const int stride = gridDim.x * 256;
  const int t0 = blockIdx.x * 256 + threadIdx.x;
  for (int i = t0; i < 768 * 128; i += stride) {
    float v = (i < 384 * 128) ? twin[i] : swin[i - 384 * 128];
    wcat[i] = f2bfs(v);
  }
  for (int i = t0; i < 128 * 128; i += stride) {
    wto[i] = f2bfs(twout[i]);
    wso[i] = f2bfs(swout[i]);
  }
  for (int i = t0; i < 768; i += stride)
    biasin[i] = (i < 384) ? tbin[i] : sbin[i - 384];
  for (int i = t0; i < 128; i += stride)
    biasc[i] = tbout[i] + sbout[i];
}

// ------------------------------------------------------------ k_proj_skv ----
// Per (b,m): s_k, s_v panels in (b,m)-major layout [bm*64+t][128] so the fused
// kernel's gather reads 4KB-contiguous stretches per neighbor.
__global__ void __launch_bounds__(256) k_proj_skv(
    const float* __restrict__ x, const short* __restrict__ wcat,
    const float* __restrict__ biasin,
    short* __restrict__ sk, short* __restrict__ sv) {
  __shared__ uint4 smv[1024];
  char* sx = (char*)smv;
  const int bm = (blockIdx.x & 7) * 128 + (blockIdx.x >> 3);
  const int b = bm >> 8, m = bm & 255;
  const int tid = threadIdx.x;
#pragma unroll
  for (int it = 0; it < 8; ++it) {
    int li = it * 256 + tid;
    int row = li >> 5, c4 = li & 31;
    float4 v = reinterpret_cast<const float4*>(x)[(size_t)((b * 64 + row) * 256 + m) * 32 + c4];
    short4v s;
    s[0] = f2bfs(v.x); s[1] = f2bfs(v.y); s[2] = f2bfs(v.z); s[3] = f2bfs(v.w);
    *(short4v*)(sx + swzb(row, c4 * 4)) = s;
  }
  __syncthreads();
  const int w = tid >> 6, lane = tid & 63, lo = lane & 15, hi = lane >> 4;
  const f32x4 zf = {0.f, 0.f, 0.f, 0.f};
#pragma unroll
  for (int s4 = 0; s4 < 4; ++s4) {
    int s = w * 4 + s4;
    int p = s >> 3, ct = s & 7;
    f32x4 a4[4] = {zf, zf, zf, zf};
#pragma unroll
    for (int kc = 0; kc < 4; ++kc) {
      bf16x8 bcol = *(const bf16x8*)(wcat + (512 + 128 * p + 16 * ct + lo) * 128 + 32 * kc + 8 * hi);
#pragma unroll
      for (int rt = 0; rt < 4; ++rt) {
        bf16x8 af = *(const bf16x8*)(sx + swzb(16 * rt + lo, 32 * kc + 8 * hi));
        a4[rt] = MFMA(af, bcol, a4[rt]);
      }
    }
    float bb = biasin[512 + 128 * p + 16 * ct + lo];
    short* dst = p ? sv : sk;
#pragma unroll
    for (int rt = 0; rt < 4; ++rt)
#pragma unroll
      for (int r = 0; r < 4; ++r)
        dst[(size_t)(bm * 64 + 16 * rt + 4 * hi + r) * 128 + 16 * ct + lo] = f2bfs(a4[rt][r] + bb);
  }
}

// ------------------------------------------------------- fused attn block ----
// One 64-key attention block over head-pair of wave w; accumulates o and ls.
DEVI void attn_block(const char* qbuf, const char* kbuf, const char* vbuf,
                     int w, int lo, int hi, int colq,
                     f32x4 (*o)[4], float (*ls)[4]) {
  const f32x4 zf = {0.f, 0.f, 0.f, 0.f};
#pragma unroll
  for (int hh = 0; hh < 2; ++hh) {
    const int hc = (2 * w + hh) * 16;
    bf16x8 qf[4];
#pragma unroll
    for (int qt = 0; qt < 4; ++qt)
      qf[qt] = *(const bf16x8*)(qbuf + swzb(16 * qt + lo, hc + colq));
#pragma unroll
    for (int kc = 0; kc < 2; ++kc) {
      bf16x8 kf0 = *(const bf16x8*)(kbuf + swzb(16 * (2 * kc) + lo, hc + colq));
      bf16x8 kf1 = *(const bf16x8*)(kbuf + swzb(16 * (2 * kc + 1) + lo, hc + colq));
      f32x4 st0[4], st1[4];
#pragma unroll
      for (int qt = 0; qt < 4; ++qt) {
        st0[qt] = MFMA(kf0, qf[qt], zf);
        st1[qt] = MFMA(kf1, qf[qt], zf);
      }
#pragma unroll
      for (int qt = 0; qt < 4; ++qt)
#pragma unroll
        for (int r = 0; r < 4; ++r) {
          float p0 = exp2f(st0[qt][r]);
          float p1 = exp2f(st1[qt][r]);
          st0[qt][r] = p0; st1[qt][r] = p1;
          ls[hh][qt] += p0 + p1;
        }
      bf16x8 vf;
#pragma unroll
      for (int i = 0; i < 8; ++i) {
        int key = 32 * kc + 16 * (i >> 2) + 4 * hi + (i & 3);
        vf[i] = *(const short*)(vbuf + swzb(key, hc + lo));
      }
#pragma unroll
      for (int qt = 0; qt < 4; ++qt) {
        bf16x8 pa;
#pragma unroll
        for (int r = 0; r < 4; ++r) {
          pa[r] = f2bfs(st0[qt][r]);
          pa[4 + r] = f2bfs(st1[qt][r]);
        }
        o[hh][qt] = MFMA(pa, vf, o[hh][qt]);
      }
    }
  }
}

DEVI void stage_o(char* dst, f32x4 (*o)[4], float (*ls)[4], int w, int lo, int hi) {
#pragma unroll
  for (int hh = 0; hh < 2; ++hh) {
    const int hc = (2 * w + hh) * 16;
#pragma unroll
    for (int qt = 0; qt < 4; ++qt) {
      float l = ls[hh][qt];
      l += __shfl_xor(l, 16);
      l += __shfl_xor(l, 32);
      float linv = 1.0f / l;
#pragma unroll
      for (int r = 0; r < 4; ++r) {
        float lr = __shfl(linv, 4 * hi + r);
        *(short*)(dst + swzb(16 * qt + 4 * hi + r, hc + lo)) = f2bfs(o[hh][qt][r] * lr);
      }
    }
  }
}

DEVI void outproj(const char* abuf, const short* __restrict__ wmat,
                  int w, int lo, int hi, f32x4* acc) {
#pragma unroll
  for (int kc = 0; kc < 4; ++kc) {
    bf16x8 a = *(const bf16x8*)(abuf + swzb(16 * w + lo, 32 * kc + 8 * hi));
#pragma unroll
    for (int ct = 0; ct < 8; ++ct) {
      bf16x8 bf = *(const bf16x8*)(wmat + (16 * ct + lo) * 128 + 32 * kc + 8 * hi);
      acc[ct] = MFMA(a, bf, acc[ct]);
    }
  }
}

// --------------------------------------------------------------- k_fused ----
__global__ void __launch_bounds__(256) k_fused(
    const float* __restrict__ x, const short* __restrict__ wcat,
    const float* __restrict__ biasin, const short* __restrict__ wto,
    const short* __restrict__ wso, const float* __restrict__ biasc,
    const short* __restrict__ skp, const short* __restrict__ svp,
    const int* __restrict__ route, float* __restrict__ out) {
  __shared__ uint4 smv[4096];  // 64 KiB
  char* bufX = (char*)smv;          // x -> O_t stage -> O_s stage
  char* bufQ = bufX + 16384;        // t_q -> s_q
  char* bufK = bufX + 32768;        // t_k -> spatial K chunks
  char* bufV = bufX + 49152;        // t_v -> spatial V chunks
  const int bm = (blockIdx.x & 7) * 128 + (blockIdx.x >> 3);  // XCD-chunked
  const int b = bm >> 8, m = bm & 255;
  const int tid = threadIdx.x;
  const int rn0 = route[m * 4 + 0], rn1 = route[m * 4 + 1];
  const int rn2 = route[m * 4 + 2], rn3 = route[m * 4 + 3];
  const uint4* skp4 = (const uint4*)skp;
  const uint4* svp4 = (const uint4*)svp;
  const f32x4 zf = {0.f, 0.f, 0.f, 0.f};

  uint4 pkA[4], pvA[4], pkB[4], pvB[4];

#define ISSUE(PK, PV, C)                                                        \
  do {                                                                          \
    _Pragma("unroll") for (int it = 0; it < 4; ++it) {                          \
      int nb = (it == 0) ? rn0 : (it == 1) ? rn1 : (it == 2) ? rn2 : rn3;       \
      size_t idx = ((size_t)(b * 256 + nb) * 64 + 16 * (C) + (tid >> 4)) * 16 + \
                   (tid & 15);                                                  \
      PK[it] = skp4[idx];                                                       \
      PV[it] = svp4[idx];                                                       \
    }                                                                           \
  } while (0)

#define WRITEKV(PK, PV)                                      \
  do {                                                       \
    _Pragma("unroll") for (int it = 0; it < 4; ++it) {       \
      int key = it * 16 + (tid >> 4);                        \
      int o_ = swzb(key, (tid & 15) * 8);                    \
      *(uint4*)(bufK + o_) = PK[it];                         \
      *(uint4*)(bufV + o_) = PV[it];                         \
    }                                                        \
  } while (0)

  // ---- A: prefetch spatial chunk 0; load x tile -> bufX (bf16, swizzled)
  ISSUE(pkA, pvA, 0);
#pragma unroll
  for (int it = 0; it < 8; ++it) {
    int li = it * 256 + tid;
    int row = li >> 5, c4 = li & 31;
    float4 v = reinterpret_cast<const float4*>(x)[(size_t)((b * 64 + row) * 256 + m) * 32 + c4];
    short4v s;
    s[0] = f2bfs(v.x); s[1] = f2bfs(v.y); s[2] = f2bfs(v.z); s[3] = f2bfs(v.w);
    *(short4v*)(bufX + swzb(row, c4 * 4)) = s;
  }
  __syncthreads();

  const int w = tid >> 6, lane = tid & 63, lo = lane & 15, hi = lane >> 4;
  const int colq = 8 * (hi & 1);

  // ---- B: t_q/t_k/t_v projections, 24 column strips over 4 waves
#pragma unroll
  for (int s6 = 0; s6 < 6; ++s6) {
    int s = w * 6 + s6;
    int p = s >> 3, ct = s & 7;
    f32x4 a4[4] = {zf, zf, zf, zf};
#pragma unroll
    for (int kc = 0; kc < 4; ++kc) {
      bf16x8 bcol = *(const bf16x8*)(wcat + (128 * p + 16 * ct + lo) * 128 + 32 * kc + 8 * hi);
#pragma unroll
      for (int rt = 0; rt < 4; ++rt) {
        bf16x8 af = *(const bf16x8*)(bufX + swzb(16 * rt + lo, 32 * kc + 8 * hi));
        a4[rt] = MFMA(af, bcol, a4[rt]);
      }
    }
    float bb = biasin[128 * p + 16 * ct + lo];
    float sc = (p == 0) ? QSCALE : 1.0f;
    char* pb = bufQ + p * 16384;
#pragma unroll
    for (int rt = 0; rt < 4; ++rt)
#pragma unroll
      for (int r = 0; r < 4; ++r)
        *(short*)(pb + swzb(16 * rt + 4 * hi + r, 16 * ct + lo)) = f2bfs((a4[rt][r] + bb) * sc);
  }
  __syncthreads();

  // ---- C: temporal attention
  f32x4 o_t[2][4];
  float ls_t[2][4];
#pragma unroll
  for (int hh = 0; hh < 2; ++hh)
#pragma unroll
    for (int qt = 0; qt < 4; ++qt) { o_t[hh][qt] = zf; ls_t[hh][qt] = 0.f; }
  attn_block(bufQ, bufK, bufV, w, lo, hi, colq, o_t, ls_t);
  __syncthreads();

  // ---- B2: chunk0 -> LDS, issue chunk1; s_q projection -> bufQ (overwrites t_q)
  WRITEKV(pkA, pvA);
  ISSUE(pkB, pvB, 1);
#pragma unroll
  for (int s2 = 0; s2 < 2; ++s2) {
    int ct = w * 2 + s2;
    f32x4 a4[4] = {zf, zf, zf, zf};
#pragma unroll
    for (int kc = 0; kc < 4; ++kc) {
      bf16x8 bcol = *(const bf16x8*)(wcat + (384 + 16 * ct + lo) * 128 + 32 * kc + 8 * hi);
#pragma unroll
      for (int rt = 0; rt < 4; ++rt) {
        bf16x8 af = *(const bf16x8*)(bufX + swzb(16 * rt + lo, 32 * kc + 8 * hi));
        a4[rt] = MFMA(af, bcol, a4[rt]);
      }
    }
    float bb = biasin[384 + 16 * ct + lo];
#pragma unroll
    for (int rt = 0; rt < 4; ++rt)
#pragma unroll
      for (int r = 0; r < 4; ++r)
        *(short*)(bufQ + swzb(16 * rt + 4 * hi + r, 16 * ct + lo)) = f2bfs((a4[rt][r] + bb) * QSCALE);
  }
  __syncthreads();

  // ---- D: stage normalized O_t -> bufX (x is dead now)
  stage_o(bufX, o_t, ls_t, w, lo, hi);
  __syncthreads();

  // ---- E: temporal out-proj (regs) + spatial chunk 0
  f32x4 accT[8];
#pragma unroll
  for (int ct = 0; ct < 8; ++ct) accT[ct] = zf;
  outproj(bufX, wto, w, lo, hi, accT);

  f32x4 o_s[2][4];
  float ls_s[2][4];
#pragma unroll
  for (int hh = 0; hh < 2; ++hh)
#pragma unroll
    for (int qt = 0; qt < 4; ++qt) { o_s[hh][qt] = zf; ls_s[hh][qt] = 0.f; }
  attn_block(bufQ, bufK, bufV, w, lo, hi, colq, o_s, ls_s);
  __syncthreads();

  WRITEKV(pkB, pvB);
  ISSUE(pkA, pvA, 2);
  __syncthreads();
  attn_block(bufQ, bufK, bufV, w, lo, hi, colq, o_s, ls_s);  // chunk 1
  __syncthreads();

  WRITEKV(pkA, pvA);
  ISSUE(pkB, pvB, 3);
  __syncthreads();
  attn_block(bufQ, bufK, bufV, w, lo, hi, colq, o_s, ls_s);  // chunk 2
  __syncthreads();

  WRITEKV(pkB, pvB);
  __syncthreads();
  attn_block(bufQ, bufK, bufV, w, lo, hi, colq, o_s, ls_s);  // chunk 3

  // ---- G: stage normalized O_s -> bufX
  stage_o(bufX, o_s, ls_s, w, lo, hi);
  __syncthreads();

  // ---- H: spatial out-proj; combine with accT + bias; single out write
  f32x4 accS[8];
#pragma unroll
  for (int ct = 0; ct < 8; ++ct) accS[ct] = zf;
  outproj(bufX, wso, w, lo, hi, accS);
#pragma unroll
  for (int ct = 0; ct < 8; ++ct) {
    float bb = biasc[16 * ct + lo];
#pragma unroll
    for (int r = 0; r < 4; ++r) {
      int t = 16 * w + 4 * hi + r;
      out[(size_t)((b * 64 + t) * 256 + m) * 128 + 16 * ct + lo] = accT[ct][r] + accS[ct][r] + bb;
    }
  }
#undef ISSUE
#undef WRITEKV
}

// ---------------------------------------------------------------- launch ----
extern "C" void kernel_launch(void* const* d_in, const int* in_sizes, int n_in,
                              void* d_out, int out_size, void* d_ws, size_t ws_size,
                              hipStream_t stream) {
  (void)in_sizes; (void)n_in; (void)out_size; (void)ws_size;
  const float* x = (const float*)d_in[0];
  const int* route = (const int*)d_in[1];
  const float* twin = (const float*)d_in[2];
  const float* tbin = (const float*)d_in[3];
  const float* twout = (const float*)d_in[4];
  const float* tbout = (const float*)d_in[5];
  const float* swin = (const float*)d_in[6];
  const float* sbin = (const float*)d_in[7];
  const float* swout = (const float*)d_in[8];
  const float* sbout = (const float*)d_in[9];

  char* ws = (char*)d_ws;
  size_t off = 0;
  auto alloc = [&](size_t bytes) {
    char* p = ws + off;
    off += (bytes + 255) & ~(size_t)255;
    return p;
  };
  short* wcat = (short*)alloc(768 * 128 * 2);
  float* biasin = (float*)alloc(768 * 4);
  short* wto = (short*)alloc(128 * 128 * 2);
  short* wso = (short*)alloc(128 * 128 * 2);
  float* biasc = (float*)alloc(128 * 4);
  short* sk = (short*)alloc((size_t)65536 * 128 * 2);
  short* sv = (short*)alloc((size_t)65536 * 128 * 2);
  float* out = (float*)d_out;

  k_prep<<<dim3(64), dim3(256), 0, stream>>>(twin, tbin, twout, tbout, swin, sbin,
                                             swout, sbout, wcat, biasin, wto, wso, biasc);
  k_proj_skv<<<dim3(1024), dim3(256), 0, stream>>>(x, wcat, biasin, sk, sv);
  k_fused<<<dim3(1024), dim3(256), 0, stream>>>(x, wcat, biasin, wto, wso, biasc,
                                                sk, sv, route, out);
}

// Round 3
// 210.613 us; speedup vs baseline: 1.3284x; 1.3284x over previous
//
#include <hip/hip_runtime.h>
#include <hip/hip_bf16.h>

// STSA R3: parallelism-first split.
//  k_prep    : weights -> bf16
//  k_fused_t : per (b,m): x->LDS, all 6 projections (t_q/t_k LDS, s_q/s_k/s_v
//              global, t_v regs->LDS), temporal attn, t-out-proj -> out (f32).
//  k_attn_s  : per (b,m,chunk-pair): 128 of 256 spatial keys; writes
//              UNNORMALIZED partial O (bf16) + partial l (f32). chain=2.
//  k_comb    : per (b,m): combine partials, normalize, s-out-proj, out += +bias.
// All matmuls mfma_f32_16x16x32_bf16. Softmax scale folded into Q
// (0.25*log2e*0.5; 0.5 compensates hd=16 duplicated into both K-halves),
// exp2, no max-subtract (scores tiny), normalize at combine.

typedef __attribute__((ext_vector_type(8))) short bf16x8;
typedef __attribute__((ext_vector_type(4))) short short4v;
typedef __attribute__((ext_vector_type(4))) float f32x4;

#define DEVI static __device__ __forceinline__
#define MFMA(a, b, c) __builtin_amdgcn_mfma_f32_16x16x32_bf16(a, b, c, 0, 0, 0)

static constexpr float QSCALE = 0.25f * 1.44269504088896340736f * 0.5f;

DEVI short f2bfs(float f) {
  __hip_bfloat16 h = __float2bfloat16(f);
  return __builtin_bit_cast(short, h);
}
DEVI float bf2f(short s) {
  unsigned u = ((unsigned)(unsigned short)s) << 16;
  return __builtin_bit_cast(float, u);
}

// 64 rows x 128 bf16 LDS tile, 256B rows, XOR swizzle on write AND read.
DEVI int swzb(int row, int colh) {
  return (row * 256 + colh * 2) ^ ((row & 7) << 4);
}

// ---------------------------------------------------------------- k_prep ----
__global__ void __launch_bounds__(256) k_prep(
    const float* __restrict__ twin, const float* __restrict__ tbin,
    const float* __restrict__ twout, const float* __restrict__ tbout,
    const float* __restrict__ swin, const float* __restrict__ sbin,
    const float* __restrict__ swout, const float* __restrict__ sbout,
    short* __restrict__ wcat, float* __restrict__ biasin,
    short* __restrict__ wto, short* __restrict__ wso, float* __restrict__ biasc) {
  const int stride = gridDim.x * 256;
  const int t0 = blockIdx.x * 256 + threadIdx.x;
  for (int i = t0; i < 768 * 128; i += stride) {
    float v = (i < 384 * 128) ? twin[i] : swin[i - 384 * 128];
    wcat[i] = f2bfs(v);
  }
  for (int i = t0; i < 128 * 128; i += stride) {
    wto[i] = f2bfs(twout[i]);
    wso[i] = f2bfs(swout[i]);
  }
  for (int i = t0; i < 768; i += stride)
    biasin[i] = (i < 384) ? tbin[i] : sbin[i - 384];
  for (int i = t0; i < 128; i += stride)
    biasc[i] = tbout[i] + sbout[i];
}

// --------------------------------------------------------------- helpers ----
// One 16-col projection strip: a4[rt] = X(64x128) @ wcat_row(wrow..)^T fragment.
DEVI void proj_strip(const char* sx, const short* __restrict__ wcat,
                     int wrow, int lo, int hi, f32x4* a4) {
  const f32x4 zf = {0.f, 0.f, 0.f, 0.f};
#pragma unroll
  for (int rt = 0; rt < 4; ++rt) a4[rt] = zf;
#pragma unroll
  for (int kc = 0; kc < 4; ++kc) {
    bf16x8 bcol = *(const bf16x8*)(wcat + (wrow)*128 + 32 * kc + 8 * hi);
#pragma unroll
    for (int rt = 0; rt < 4; ++rt) {
      bf16x8 af = *(const bf16x8*)(sx + swzb(16 * rt + lo, 32 * kc + 8 * hi));
      a4[rt] = MFMA(af, bcol, a4[rt]);
    }
  }
}

// One 64-key attention block for head-pair of wave w; accumulates o and ls.
DEVI void attn_block(const char* qbuf, const char* kbuf, const char* vbuf,
                     int w, int lo, int hi, int colq,
                     f32x4 (*o)[4], float (*ls)[4]) {
  const f32x4 zf = {0.f, 0.f, 0.f, 0.f};
#pragma unroll
  for (int hh = 0; hh < 2; ++hh) {
    const int hc = (2 * w + hh) * 16;
    bf16x8 qf[4];
#pragma unroll
    for (int qt = 0; qt < 4; ++qt)
      qf[qt] = *(const bf16x8*)(qbuf + swzb(16 * qt + lo, hc + colq));
#pragma unroll
    for (int kc = 0; kc < 2; ++kc) {
      bf16x8 kf0 = *(const bf16x8*)(kbuf + swzb(16 * (2 * kc) + lo, hc + colq));
      bf16x8 kf1 = *(const bf16x8*)(kbuf + swzb(16 * (2 * kc + 1) + lo, hc + colq));
      f32x4 st0[4], st1[4];
#pragma unroll
      for (int qt = 0; qt < 4; ++qt) {
        st0[qt] = MFMA(kf0, qf[qt], zf);
        st1[qt] = MFMA(kf1, qf[qt], zf);
      }
#pragma unroll
      for (int qt = 0; qt < 4; ++qt)
#pragma unroll
        for (int r = 0; r < 4; ++r) {
          float p0 = exp2f(st0[qt][r]);
          float p1 = exp2f(st1[qt][r]);
          st0[qt][r] = p0; st1[qt][r] = p1;
          ls[hh][qt] += p0 + p1;
        }
      bf16x8 vf;
#pragma unroll
      for (int i = 0; i < 8; ++i) {
        int key = 32 * kc + 16 * (i >> 2) + 4 * hi + (i & 3);
        vf[i] = *(const short*)(vbuf + swzb(key, hc + lo));
      }
#pragma unroll
      for (int qt = 0; qt < 4; ++qt) {
        bf16x8 pa;
#pragma unroll
        for (int r = 0; r < 4; ++r) {
          pa[r] = f2bfs(st0[qt][r]);
          pa[4 + r] = f2bfs(st1[qt][r]);
        }
        o[hh][qt] = MFMA(pa, vf, o[hh][qt]);
      }
    }
  }
}

DEVI void outproj(const char* abuf, const short* __restrict__ wmat,
                  int w, int lo, int hi, f32x4* acc) {
#pragma unroll
  for (int kc = 0; kc < 4; ++kc) {
    bf16x8 a = *(const bf16x8*)(abuf + swzb(16 * w + lo, 32 * kc + 8 * hi));
#pragma unroll
    for (int ct = 0; ct < 8; ++ct) {
      bf16x8 bf = *(const bf16x8*)(wmat + (16 * ct + lo) * 128 + 32 * kc + 8 * hi);
      acc[ct] = MFMA(a, bf, acc[ct]);
    }
  }
}

// -------------------------------------------------------------- k_fused_t ----
__global__ void __launch_bounds__(256) k_fused_t(
    const float* __restrict__ x, const short* __restrict__ wcat,
    const float* __restrict__ biasin, const short* __restrict__ wto,
    short* __restrict__ sq, short* __restrict__ sk, short* __restrict__ sv,
    float* __restrict__ out) {
  __shared__ uint4 smv[3072];  // 48 KiB
  char* bufX = (char*)smv;     // x -> t_v -> (attn V)
  char* bufQ = bufX + 16384;   // t_q -> O_t stage
  char* bufK = bufX + 32768;   // t_k
  const int bm = blockIdx.x, b = bm >> 8, m = bm & 255;
  const int tid = threadIdx.x;

  // x tile -> bufX (bf16, swizzled)
#pragma unroll
  for (int it = 0; it < 8; ++it) {
    int li = it * 256 + tid;
    int row = li >> 5, c4 = li & 31;
    float4 v = reinterpret_cast<const float4*>(x)[(size_t)((b * 64 + row) * 256 + m) * 32 + c4];
    short4v s;
    s[0] = f2bfs(v.x); s[1] = f2bfs(v.y); s[2] = f2bfs(v.z); s[3] = f2bfs(v.w);
    *(short4v*)(bufX + swzb(row, c4 * 4)) = s;
  }
  __syncthreads();

  const int w = tid >> 6, lane = tid & 63, lo = lane & 15, hi = lane >> 4;
  const int colq = 8 * (hi & 1);
  f32x4 a4[4];

  // Phase A: t_q -> bufQ (scaled), t_k -> bufK
#pragma unroll
  for (int p = 0; p < 2; ++p) {
    char* pb = (p == 0) ? bufQ : bufK;
    float sc = (p == 0) ? QSCALE : 1.0f;
#pragma unroll
    for (int j = 0; j < 2; ++j) {
      int ct = 2 * w + j;
      proj_strip(bufX, wcat, p * 128 + 16 * ct + lo, lo, hi, a4);
      float bb = biasin[p * 128 + 16 * ct + lo];
#pragma unroll
      for (int rt = 0; rt < 4; ++rt)
#pragma unroll
        for (int r = 0; r < 4; ++r)
          *(short*)(pb + swzb(16 * rt + 4 * hi + r, 16 * ct + lo)) =
              f2bfs((a4[rt][r] + bb) * sc);
    }
  }

  // Phase B: t_v -> regs (written to bufX after barrier)
  f32x4 tvacc[2][4];
#pragma unroll
  for (int j = 0; j < 2; ++j) {
    int ct = 2 * w + j;
    proj_strip(bufX, wcat, 2 * 128 + 16 * ct + lo, lo, hi, tvacc[j]);
    float bb = biasin[2 * 128 + 16 * ct + lo];
#pragma unroll
    for (int rt = 0; rt < 4; ++rt)
#pragma unroll
      for (int r = 0; r < 4; ++r) tvacc[j][rt][r] += bb;
  }

  // Phase C: s_q / s_k / s_v -> global (bm-major [bm*64+t][128])
#pragma unroll
  for (int p = 3; p < 6; ++p) {
    short* dst = (p == 3) ? sq : (p == 4) ? sk : sv;
    float sc = (p == 3) ? QSCALE : 1.0f;
#pragma unroll
    for (int j = 0; j < 2; ++j) {
      int ct = 2 * w + j;
      proj_strip(bufX, wcat, p * 128 + 16 * ct + lo, lo, hi, a4);
      float bb = biasin[p * 128 + 16 * ct + lo];
#pragma unroll
      for (int rt = 0; rt < 4; ++rt)
#pragma unroll
        for (int r = 0; r < 4; ++r)
          dst[(size_t)(bm * 64 + 16 * rt + 4 * hi + r) * 128 + 16 * ct + lo] =
              f2bfs((a4[rt][r] + bb) * sc);
    }
  }
  __syncthreads();

  // t_v -> bufX (x dead)
#pragma unroll
  for (int j = 0; j < 2; ++j) {
    int ct = 2 * w + j;
#pragma unroll
    for (int rt = 0; rt < 4; ++rt)
#pragma unroll
      for (int r = 0; r < 4; ++r)
        *(short*)(bufX + swzb(16 * rt + 4 * hi + r, 16 * ct + lo)) = f2bfs(tvacc[j][rt][r]);
  }
  __syncthreads();

  // temporal attention
  const f32x4 zf = {0.f, 0.f, 0.f, 0.f};
  f32x4 o_t[2][4];
  float ls_t[2][4];
#pragma unroll
  for (int hh = 0; hh < 2; ++hh)
#pragma unroll
    for (int qt = 0; qt < 4; ++qt) { o_t[hh][qt] = zf; ls_t[hh][qt] = 0.f; }
  attn_block(bufQ, bufK, bufX, w, lo, hi, colq, o_t, ls_t);
  __syncthreads();

  // stage normalized O_t -> bufQ (swizzled)
#pragma unroll
  for (int hh = 0; hh < 2; ++hh) {
    const int hc = (2 * w + hh) * 16;
#pragma unroll
    for (int qt = 0; qt < 4; ++qt) {
      float l = ls_t[hh][qt];
      l += __shfl_xor(l, 16);
      l += __shfl_xor(l, 32);
      float linv = 1.0f / l;
#pragma unroll
      for (int r = 0; r < 4; ++r) {
        float lr = __shfl(linv, 4 * hi + r);
        *(short*)(bufQ + swzb(16 * qt + 4 * hi + r, hc + lo)) = f2bfs(o_t[hh][qt][r] * lr);
      }
    }
  }
  __syncthreads();

  // temporal out-proj -> out (no bias; k_comb adds combined bias)
  f32x4 accT[8];
#pragma unroll
  for (int ct = 0; ct < 8; ++ct) accT[ct] = zf;
  outproj(bufQ, wto, w, lo, hi, accT);
#pragma unroll
  for (int ct = 0; ct < 8; ++ct)
#pragma unroll
    for (int r = 0; r < 4; ++r) {
      int t = 16 * w + 4 * hi + r;
      out[(size_t)((b * 64 + t) * 256 + m) * 128 + 16 * ct + lo] = accT[ct][r];
    }
}

// --------------------------------------------------------------- k_attn_s ----
// blk = bm*2 + cp; handles chunks 2cp, 2cp+1 (64 keys each). Writes unnorm
// partial O (bf16 [blk][64][128]) + partial l (f32 [blk][8*64]).
__global__ void __launch_bounds__(256) k_attn_s(
    const short* __restrict__ sq, const short* __restrict__ skp,
    const short* __restrict__ svp, const int* __restrict__ route,
    uint4* __restrict__ O_ws, float* __restrict__ lws) {
  __shared__ uint4 smv[3072];
  char* bufQ = (char*)smv;
  char* bufK = bufQ + 16384;
  char* bufV = bufQ + 32768;
  const int blk = blockIdx.x, bm = blk >> 1, cp = blk & 1;
  const int b = bm >> 8, m = bm & 255;
  const int tid = threadIdx.x;
  const int rn0 = route[m * 4 + 0], rn1 = route[m * 4 + 1];
  const int rn2 = route[m * 4 + 2], rn3 = route[m * 4 + 3];
  const uint4* skp4 = (const uint4*)skp;
  const uint4* svp4 = (const uint4*)svp;

#define LOADKV(C)                                                              \
  do {                                                                         \
    _Pragma("unroll") for (int it = 0; it < 4; ++it) {                         \
      int li = it * 256 + tid;                                                 \
      int key = li >> 4, s16 = li & 15;                                        \
      int kk = key & 3;                                                        \
      int nb = kk == 0 ? rn0 : kk == 1 ? rn1 : kk == 2 ? rn2 : rn3;            \
      size_t srow = ((size_t)(b * 256 + nb) * 64 + 16 * (C) + (key >> 2)) * 16 \
                    + s16;                                                     \
      int o_ = swzb(key, s16 * 8);                                             \
      *(uint4*)(bufK + o_) = skp4[srow];                                       \
      *(uint4*)(bufV + o_) = svp4[srow];                                       \
    }                                                                          \
  } while (0)

  // q + chunk c0 loads (one stretch, no barrier between)
#pragma unroll
  for (int it = 0; it < 4; ++it) {
    int li = it * 256 + tid;
    *(uint4*)(bufQ + swzb(li >> 4, (li & 15) * 8)) =
        ((const uint4*)(sq + (size_t)bm * 8192))[li];
  }
  LOADKV(2 * cp);
  __syncthreads();

  const int w = tid >> 6, lane = tid & 63, lo = lane & 15, hi = lane >> 4;
  const int colq = 8 * (hi & 1);
  const f32x4 zf = {0.f, 0.f, 0.f, 0.f};
  f32x4 o_s[2][4];
  float ls_s[2][4];
#pragma unroll
  for (int hh = 0; hh < 2; ++hh)
#pragma unroll
    for (int qt = 0; qt < 4; ++qt) { o_s[hh][qt] = zf; ls_s[hh][qt] = 0.f; }

  attn_block(bufQ, bufK, bufV, w, lo, hi, colq, o_s, ls_s);
  __syncthreads();
  LOADKV(2 * cp + 1);
  __syncthreads();
  attn_block(bufQ, bufK, bufV, w, lo, hi, colq, o_s, ls_s);
  __syncthreads();

  // stage UNNORMALIZED O -> bufK (plain [64][128] bf16) + write partial l
#pragma unroll
  for (int hh = 0; hh < 2; ++hh) {
    const int hc = (2 * w + hh) * 16;
#pragma unroll
    for (int qt = 0; qt < 4; ++qt) {
      float l = ls_s[hh][qt];
      l += __shfl_xor(l, 16);
      l += __shfl_xor(l, 32);
      if (hi == 0) lws[(size_t)blk * 512 + (2 * w + hh) * 64 + 16 * qt + lo] = l;
#pragma unroll
      for (int r = 0; r < 4; ++r)
        *(short*)(bufK + (16 * qt + 4 * hi + r) * 256 + (hc + lo) * 2) =
            f2bfs(o_s[hh][qt][r]);
    }
  }
  __syncthreads();
#pragma unroll
  for (int it = 0; it < 4; ++it) {
    int li = it * 256 + tid;
    O_ws[(size_t)blk * 1024 + li] = ((uint4*)bufK)[li];
  }
#undef LOADKV
}

// ----------------------------------------------------------------- k_comb ----
__global__ void __launch_bounds__(256) k_comb(
    const uint4* __restrict__ O_ws, const float* __restrict__ lws,
    const short* __restrict__ wso, const float* __restrict__ biasc,
    float* __restrict__ out) {
  __shared__ uint4 s4[1024];   // 16 KiB staged normalized O_s
  __shared__ float lb[512];
  char* bufS = (char*)s4;
  const int bm = blockIdx.x, b = bm >> 8, m = bm & 255;
  const int tid = threadIdx.x;
  const size_t blk0 = (size_t)bm * 2, blk1 = blk0 + 1;
#pragma unroll
  for (int j = 0; j < 2; ++j) {
    int i = j * 256 + tid;
    lb[i] = 1.0f / (lws[blk0 * 512 + i] + lws[blk1 * 512 + i]);
  }
  __syncthreads();
#pragma unroll
  for (int it = 0; it < 4; ++it) {
    int li = it * 256 + tid;
    uint4 u0 = O_ws[blk0 * 1024 + li];
    uint4 u1 = O_ws[blk1 * 1024 + li];
    int row = li >> 4, col8 = (li & 15) * 8, head = (li & 15) >> 1;
    float linv = lb[head * 64 + row];
    short4v ra, rb;
    const short* p0 = (const short*)&u0;
    const short* p1 = (const short*)&u1;
#pragma unroll
    for (int j = 0; j < 4; ++j) ra[j] = f2bfs((bf2f(p0[j]) + bf2f(p1[j])) * linv);
#pragma unroll
    for (int j = 0; j < 4; ++j) rb[j] = f2bfs((bf2f(p0[4 + j]) + bf2f(p1[4 + j])) * linv);
    char* dst = bufS + swzb(row, col8);
    *(short4v*)dst = ra;
    *(short4v*)(dst + 8) = rb;
  }
  __syncthreads();
  const int w = tid >> 6, lane = tid & 63, lo = lane & 15, hi = lane >> 4;
  const f32x4 zf = {0.f, 0.f, 0.f, 0.f};
  f32x4 accS[8];
#pragma unroll
  for (int ct = 0; ct < 8; ++ct) accS[ct] = zf;
  outproj(bufS, wso, w, lo, hi, accS);
#pragma unroll
  for (int ct = 0; ct < 8; ++ct) {
    float bb = biasc[16 * ct + lo];
#pragma unroll
    for (int r = 0; r < 4; ++r) {
      int t = 16 * w + 4 * hi + r;
      size_t idx = (size_t)((b * 64 + t) * 256 + m) * 128 + 16 * ct + lo;
      out[idx] = out[idx] + accS[ct][r] + bb;
    }
  }
}

// ---------------------------------------------------------------- launch ----
extern "C" void kernel_launch(void* const* d_in, const int* in_sizes, int n_in,
                              void* d_out, int out_size, void* d_ws, size_t ws_size,
                              hipStream_t stream) {
  (void)in_sizes; (void)n_in; (void)out_size; (void)ws_size;
  const float* x = (const float*)d_in[0];
  const int* route = (const int*)d_in[1];
  const float* twin = (const float*)d_in[2];
  const float* tbin = (const float*)d_in[3];
  const float* twout = (const float*)d_in[4];
  const float* tbout = (const float*)d_in[5];
  const float* swin = (const float*)d_in[6];
  const float* sbin = (const float*)d_in[7];
  const float* swout = (const float*)d_in[8];
  const float* sbout = (const float*)d_in[9];

  char* ws = (char*)d_ws;
  size_t off = 0;
  auto alloc = [&](size_t bytes) {
    char* p = ws + off;
    off += (bytes + 255) & ~(size_t)255;
    return p;
  };
  short* wcat = (short*)alloc(768 * 128 * 2);
  float* biasin = (float*)alloc(768 * 4);
  short* wto = (short*)alloc(128 * 128 * 2);
  short* wso = (short*)alloc(128 * 128 * 2);
  float* biasc = (float*)alloc(128 * 4);
  short* sq = (short*)alloc((size_t)65536 * 128 * 2);
  short* sk = (short*)alloc((size_t)65536 * 128 * 2);
  short* sv = (short*)alloc((size_t)65536 * 128 * 2);
  uint4* O_ws = (uint4*)alloc((size_t)2048 * 16384);
  float* lws = (float*)alloc((size_t)2048 * 512 * 4);
  float* out = (float*)d_out;

  k_prep<<<dim3(64), dim3(256), 0, stream>>>(twin, tbin, twout, tbout, swin, sbin,
                                             swout, sbout, wcat, biasin, wto, wso, biasc);
  k_fused_t<<<dim3(1024), dim3(256), 0, stream>>>(x, wcat, biasin, wto, sq, sk, sv, out);
  k_attn_s<<<dim3(2048), dim3(256), 0, stream>>>(sq, sk, sv, route, O_ws, lws);
  k_comb<<<dim3(1024), dim3(256), 0, stream>>>(O_ws, lws, wso, biasc, out);
}